// Round 7
// baseline (3968.454 us; speedup 1.0000x reference)
//
#include <hip/hip_runtime.h>
#include <cmath>
#include <cstdint>

#define D_FEAT 6
#define T_SEQ  60
#define HID    256
#define G3     768
#define NROW   2048
#define NSAMP  20480

__device__ __forceinline__ float sigmoidf_(float x) { return 1.0f / (1.0f + expf(-x)); }

// ---------------------------------------------------------------- weight prep
struct PrepArgs {
  const float* src[9];
  float* dst[9];
  int N[9], K[9], ro[9], pk[9];
};

__global__ void prep_weights(PrepArgs a) {
  int seg = blockIdx.y;
  const float* S = a.src[seg];
  float* D = a.dst[seg];
  int N = a.N[seg], K = a.K[seg], ro = a.ro[seg], pk = a.pk[seg];
  int total = N * K;
  for (int i = blockIdx.x * blockDim.x + threadIdx.x; i < total; i += gridDim.x * blockDim.x) {
    int n = i / K, k = i - n * K;
    if (pk) {
      // packed layout for GRU: [k/4][u][col][k%4], u = n>>8, col = n&255
      int u = n >> 8, cn = n & 255;
      int kg = k + ro;
      D[(size_t)((kg >> 2) * 3 + u) * 1024 + cn * 4 + (kg & 3)] = S[i];
    } else {
      D[(size_t)(k + ro) * N + n] = S[i];   // WT[k][n] = W[n][k]
    }
  }
}

// ---------------------------------------------------------------- persistent fused GRU v10
// Grid 256 x 512 threads (proven-clean shape: VGPR budget up to 256 at
// 2 waves/SIMD, 1 block/CU by LDS). DS-TRAFFIC FIX: v3 and v9 both pinned at
// 58% VALUBusy with ~6144 ds_read_b128/CU/step (A broadcast reads) -- the LDS
// return path was the co-bottleneck. Now thread (cp = tid&127, q = tid>>7)
// covers TWO cols {cp, cp+128} x quarter-K (64 k): each A read feeds 6 B
// values (48 FMAs) instead of 3 (24) -> DS halved to 3072/CU/step, balanced
// against the 36.9k-cyc FMA floor. Unroll-2 B ping-pong (no v_mov recycle),
// depth-1 A prefetch. Gates on q0 (literal indices; h_old re-read from LDS).
// Exchange pitch 97 (==1 mod 32, conflict-free). 4 barriers/step.
#define FMA8(alo, ahi, b, accrow) \
  accrow[0] += alo.x * (b); accrow[1] += alo.y * (b); accrow[2] += alo.z * (b); accrow[3] += alo.w * (b); \
  accrow[4] += ahi.x * (b); accrow[5] += ahi.y * (b); accrow[6] += ahi.z * (b); accrow[7] += ahi.w * (b);

// one k-step: prefetch A(k+1) into (NL,NH), FMA with A(k)=(AL,AH) against 6 B comps
#define KS(AL, AH, NL, NH, CMP, S0, S1, S2, T0, T1, T2) \
  NL = *(const float4*)(Ap); NH = *(const float4*)(Ap + 4); Ap += 8; \
  FMA8(AL, AH, S0.CMP, pA[0]); FMA8(AL, AH, S1.CMP, pA[1]); FMA8(AL, AH, S2.CMP, pA[2]); \
  FMA8(AL, AH, T0.CMP, pB[0]); FMA8(AL, AH, T1.CMP, pB[1]); FMA8(AL, AH, T2.CMP, pB[2]);

#define ST8(dst, a0,a1,a2,a3,a4,a5,a6,a7) { \
  float4 v_; v_.x=(a0); v_.y=(a1); v_.z=(a2); v_.w=(a3); *(float4*)(dst) = v_; \
  v_.x=(a4); v_.y=(a5); v_.z=(a6); v_.w=(a7); *(float4*)((dst)+4) = v_; }

__device__ __forceinline__ void kloop64_2(const float* __restrict__ A,   // LDS, 64 k-rows (broadcast)
                                          const float* __restrict__ B,   // packed, pre-offset to (q-range, cp)
                                          float (&pA)[3][8], float (&pB)[3][8])
{
  float4 Xa0 = *(const float4*)(B);
  float4 Xa1 = *(const float4*)(B + 1024);
  float4 Xa2 = *(const float4*)(B + 2048);
  float4 Ya0 = *(const float4*)(B + 512);
  float4 Ya1 = *(const float4*)(B + 1536);
  float4 Ya2 = *(const float4*)(B + 2560);
  float4 A0l = *(const float4*)(A);
  float4 A0h = *(const float4*)(A + 4);
  float4 A1l, A1h;
  const float* Ap = A + 8;            // prefetch cursor: k+1 (over-reads 1 k at end; lands in next LDS array)
  const float* Bp = B + 3072;         // next k4 (over-reads 1 k4 at end; lands in valid ws)
  for (int kp = 0; kp < 8; ++kp) {    // 16 k4 as 8 ping-pong pairs
    float4 Xb0 = *(const float4*)(Bp);
    float4 Xb1 = *(const float4*)(Bp + 1024);
    float4 Xb2 = *(const float4*)(Bp + 2048);
    float4 Yb0 = *(const float4*)(Bp + 512);
    float4 Yb1 = *(const float4*)(Bp + 1536);
    float4 Yb2 = *(const float4*)(Bp + 2560);
    Bp += 3072;
    KS(A0l, A0h, A1l, A1h, x, Xa0, Xa1, Xa2, Ya0, Ya1, Ya2)
    KS(A1l, A1h, A0l, A0h, y, Xa0, Xa1, Xa2, Ya0, Ya1, Ya2)
    KS(A0l, A0h, A1l, A1h, z, Xa0, Xa1, Xa2, Ya0, Ya1, Ya2)
    KS(A1l, A1h, A0l, A0h, w, Xa0, Xa1, Xa2, Ya0, Ya1, Ya2)
    Xa0 = *(const float4*)(Bp);
    Xa1 = *(const float4*)(Bp + 1024);
    Xa2 = *(const float4*)(Bp + 2048);
    Ya0 = *(const float4*)(Bp + 512);
    Ya1 = *(const float4*)(Bp + 1536);
    Ya2 = *(const float4*)(Bp + 2560);
    Bp += 3072;
    KS(A0l, A0h, A1l, A1h, x, Xb0, Xb1, Xb2, Yb0, Yb1, Yb2)
    KS(A1l, A1h, A0l, A0h, y, Xb0, Xb1, Xb2, Yb0, Yb1, Yb2)
    KS(A0l, A0h, A1l, A1h, z, Xb0, Xb1, Xb2, Yb0, Yb1, Yb2)
    KS(A1l, A1h, A0l, A0h, w, Xb0, Xb1, Xb2, Yb0, Yb1, Yb2)
  }
}

__global__ __launch_bounds__(512, 1)
void gru_fused(const float* __restrict__ inp, const float* __restrict__ Whh0p,
               const float* __restrict__ Wcatp, const float* __restrict__ WTih0,
               const float* __restrict__ bih0, const float* __restrict__ bhh0,
               const float* __restrict__ bih1, const float* __restrict__ bhh1,
               float* __restrict__ hrow)
{
  // order matters: kloop A-prefetch over-reads 8 floats past an h buffer;
  // keep h buffers followed by other LDS so the stray read stays in-bounds.
  __shared__ float h0A[2048], h0B[2048];   // [col*8 + row] ping-pong
  __shared__ float h1A[2048], h1B[2048];
  __shared__ float xls[2880];              // [(i*60+t)*8 + row]
  __shared__ float exch[256 * 97];         // per col: 3 quarters x (24 | 32) slots

  const int tid = threadIdx.x;
  const int cp  = tid & 127;               // first col; second is cp+128
  const int q   = tid >> 7;                // K-quarter
  const int m0  = blockIdx.x * 8;

  for (int c = tid; c < 2880; c += 512) {
    int row = c / 360, it = c - row * 360;
    xls[it * 8 + row] = inp[(size_t)(m0 + row) * 360 + it];
  }
  for (int c = tid; c < 2048; c += 512) { h0A[c] = 0.f; h1A[c] = 0.f; }

  float bA_ih0[3], bA_hh0[3], bB_ih0[3], bB_hh0[3];
  float bA_ih1[3], bA_hh1[3], bB_ih1[3], bB_hh1[3];
  if (q == 0) {
#pragma unroll
    for (int u = 0; u < 3; ++u) {
      int oA = u * 256 + cp, oB = u * 256 + cp + 128;
      bA_ih0[u] = bih0[oA]; bA_hh0[u] = bhh0[oA];
      bB_ih0[u] = bih0[oB]; bB_hh0[u] = bhh0[oB];
      bA_ih1[u] = bih1[oA]; bA_hh1[u] = bhh1[oA];
      bB_ih1[u] = bih1[oB]; bB_hh1[u] = bhh1[oB];
    }
  }
  __syncthreads();

  const int aoff = q << 9;                 // q*64 k-rows * 8
  const float* Bhh  = Whh0p + (size_t)(q * 16) * 3072 + cp * 4;
  const float* Bct0 = Wcatp + (size_t)(q * 16) * 3072 + cp * 4;
  const float* Bct1 = Wcatp + (size_t)(64 + q * 16) * 3072 + cp * 4;
  float* exc0 = exch + cp * 97;            // col cp
  float* exc1 = exch + (cp + 128) * 97;    // col cp+128

#pragma unroll 1
  for (int t = 0; t < T_SEQ; ++t) {
    const float* h0cur = (t & 1) ? h0B : h0A;
    float*       h0nxt = (t & 1) ? h0A : h0B;
    const float* h1cur = (t & 1) ? h1B : h1A;
    float*       h1nxt = (t & 1) ? h1A : h1B;

    // ================= layer 0 =================
    float pA[3][8], pB[3][8];
#pragma unroll
    for (int u = 0; u < 3; ++u)
#pragma unroll
      for (int r = 0; r < 8; ++r) { pA[u][r] = 0.f; pB[u][r] = 0.f; }
    kloop64_2(h0cur + aoff, Bhh, pA, pB);

    if (q != 0) {
      float* e0 = exc0 + (q - 1) * 24;
      float* e1 = exc1 + (q - 1) * 24;
#pragma unroll
      for (int u = 0; u < 3; ++u) {
        ST8(e0 + u * 8, pA[u][0], pA[u][1], pA[u][2], pA[u][3], pA[u][4], pA[u][5], pA[u][6], pA[u][7]);
        ST8(e1 + u * 8, pB[u][0], pB[u][1], pB[u][2], pB[u][3], pB[u][4], pB[u][5], pB[u][6], pB[u][7]);
      }
    }
    __syncthreads();

    if (q == 0) {
#pragma unroll
      for (int s = 0; s < 3; ++s)
#pragma unroll
        for (int u = 0; u < 3; ++u)
#pragma unroll
          for (int r = 0; r < 8; ++r) {
            pA[u][r] += exc0[s * 24 + u * 8 + r];
            pB[u][r] += exc1[s * 24 + u * 8 + r];
          }
      float xwA[3][8], xwB[3][8];
#pragma unroll
      for (int u = 0; u < 3; ++u)
#pragma unroll
        for (int r = 0; r < 8; ++r) { xwA[u][r] = bA_ih0[u]; xwB[u][r] = bB_ih0[u]; }
#pragma unroll
      for (int i = 0; i < 6; ++i) {
        float4 xlo = *(const float4*)&xls[(i * 60 + t) * 8];
        float4 xhi = *(const float4*)&xls[(i * 60 + t) * 8 + 4];
#pragma unroll
        for (int u = 0; u < 3; ++u) {
          float bA = WTih0[i * G3 + u * 256 + cp];
          float bB = WTih0[i * G3 + u * 256 + cp + 128];
          xwA[u][0] += xlo.x * bA; xwA[u][1] += xlo.y * bA;
          xwA[u][2] += xlo.z * bA; xwA[u][3] += xlo.w * bA;
          xwA[u][4] += xhi.x * bA; xwA[u][5] += xhi.y * bA;
          xwA[u][6] += xhi.z * bA; xwA[u][7] += xhi.w * bA;
          xwB[u][0] += xlo.x * bB; xwB[u][1] += xlo.y * bB;
          xwB[u][2] += xlo.z * bB; xwB[u][3] += xlo.w * bB;
          xwB[u][4] += xhi.x * bB; xwB[u][5] += xhi.y * bB;
          xwB[u][6] += xhi.z * bB; xwB[u][7] += xhi.w * bB;
        }
      }
      float hoA[8], hoB[8], hnA[8], hnB[8];
#pragma unroll
      for (int r = 0; r < 8; ++r) {
        hoA[r] = h0cur[cp * 8 + r];
        hoB[r] = h0cur[(cp + 128) * 8 + r];
      }
#pragma unroll
      for (int r = 0; r < 8; ++r) {
        float rr = sigmoidf_(xwA[0][r] + (pA[0][r] + bA_hh0[0]));
        float zz = sigmoidf_(xwA[1][r] + (pA[1][r] + bA_hh0[1]));
        float nn = tanhf(xwA[2][r] + rr * (pA[2][r] + bA_hh0[2]));
        hnA[r] = (1.f - zz) * nn + zz * hoA[r];
        rr = sigmoidf_(xwB[0][r] + (pB[0][r] + bB_hh0[0]));
        zz = sigmoidf_(xwB[1][r] + (pB[1][r] + bB_hh0[1]));
        nn = tanhf(xwB[2][r] + rr * (pB[2][r] + bB_hh0[2]));
        hnB[r] = (1.f - zz) * nn + zz * hoB[r];
      }
      ST8(&h0nxt[cp * 8],         hnA[0], hnA[1], hnA[2], hnA[3], hnA[4], hnA[5], hnA[6], hnA[7]);
      ST8(&h0nxt[(cp + 128) * 8], hnB[0], hnB[1], hnB[2], hnB[3], hnB[4], hnB[5], hnB[6], hnB[7]);
    }
    __syncthreads();

    // ================= layer 1 =================
#pragma unroll
    for (int u = 0; u < 3; ++u)
#pragma unroll
      for (int r = 0; r < 8; ++r) { pA[u][r] = 0.f; pB[u][r] = 0.f; }
    kloop64_2(h0nxt + aoff, Bct0, pA, pB);      // x-part (new h0)
    float xnA[8], xnB[8];
#pragma unroll
    for (int r = 0; r < 8; ++r) {
      xnA[r] = pA[2][r]; pA[2][r] = 0.f;
      xnB[r] = pB[2][r]; pB[2][r] = 0.f;
    }
    kloop64_2(h1cur + aoff, Bct1, pA, pB);      // h-part: r/z continue, n fresh

    if (q != 0) {
      float* e0 = exc0 + (q - 1) * 32;
      float* e1 = exc1 + (q - 1) * 32;
      ST8(e0,      pA[0][0], pA[0][1], pA[0][2], pA[0][3], pA[0][4], pA[0][5], pA[0][6], pA[0][7]);
      ST8(e0 + 8,  pA[1][0], pA[1][1], pA[1][2], pA[1][3], pA[1][4], pA[1][5], pA[1][6], pA[1][7]);
      ST8(e0 + 16, xnA[0], xnA[1], xnA[2], xnA[3], xnA[4], xnA[5], xnA[6], xnA[7]);
      ST8(e0 + 24, pA[2][0], pA[2][1], pA[2][2], pA[2][3], pA[2][4], pA[2][5], pA[2][6], pA[2][7]);
      ST8(e1,      pB[0][0], pB[0][1], pB[0][2], pB[0][3], pB[0][4], pB[0][5], pB[0][6], pB[0][7]);
      ST8(e1 + 8,  pB[1][0], pB[1][1], pB[1][2], pB[1][3], pB[1][4], pB[1][5], pB[1][6], pB[1][7]);
      ST8(e1 + 16, xnB[0], xnB[1], xnB[2], xnB[3], xnB[4], xnB[5], xnB[6], xnB[7]);
      ST8(e1 + 24, pB[2][0], pB[2][1], pB[2][2], pB[2][3], pB[2][4], pB[2][5], pB[2][6], pB[2][7]);
    }
    __syncthreads();

    if (q == 0) {
#pragma unroll
      for (int s = 0; s < 3; ++s)
#pragma unroll
        for (int r = 0; r < 8; ++r) {
          pA[0][r] += exc0[s * 32 + r];
          pA[1][r] += exc0[s * 32 + 8 + r];
          xnA[r]   += exc0[s * 32 + 16 + r];
          pA[2][r] += exc0[s * 32 + 24 + r];
          pB[0][r] += exc1[s * 32 + r];
          pB[1][r] += exc1[s * 32 + 8 + r];
          xnB[r]   += exc1[s * 32 + 16 + r];
          pB[2][r] += exc1[s * 32 + 24 + r];
        }
      float hoA[8], hoB[8], hnA[8], hnB[8];
#pragma unroll
      for (int r = 0; r < 8; ++r) {
        hoA[r] = h1cur[cp * 8 + r];
        hoB[r] = h1cur[(cp + 128) * 8 + r];
      }
#pragma unroll
      for (int r = 0; r < 8; ++r) {
        float rr = sigmoidf_((pA[0][r] + bA_ih1[0]) + bA_hh1[0]);
        float zz = sigmoidf_((pA[1][r] + bA_ih1[1]) + bA_hh1[1]);
        float nn = tanhf((xnA[r] + bA_ih1[2]) + rr * (pA[2][r] + bA_hh1[2]));
        hnA[r] = (1.f - zz) * nn + zz * hoA[r];
        rr = sigmoidf_((pB[0][r] + bB_ih1[0]) + bB_hh1[0]);
        zz = sigmoidf_((pB[1][r] + bB_ih1[1]) + bB_hh1[1]);
        nn = tanhf((xnB[r] + bB_ih1[2]) + rr * (pB[2][r] + bB_hh1[2]));
        hnB[r] = (1.f - zz) * nn + zz * hoB[r];
      }
      ST8(&h1nxt[cp * 8],         hnA[0], hnA[1], hnA[2], hnA[3], hnA[4], hnA[5], hnA[6], hnA[7]);
      ST8(&h1nxt[(cp + 128) * 8], hnB[0], hnB[1], hnB[2], hnB[3], hnB[4], hnB[5], hnB[6], hnB[7]);
    }
    __syncthreads();
  }

  // final h1 lives in h1A for even T_SEQ (last t=59 odd -> h1nxt == h1A)
  if (q == 0) {
#pragma unroll
    for (int r = 0; r < 8; ++r) {
      hrow[(size_t)(m0 + r) * 256 + cp]       = h1A[cp * 8 + r];
      hrow[(size_t)(m0 + r) * 256 + cp + 128] = h1A[(cp + 128) * 8 + r];
    }
  }
}

// ---------------------------------------------------------------- generic GEMM
__global__ __launch_bounds__(256, 2)
void gemm_act(const float* __restrict__ A, const int* __restrict__ rowsrc,
              const float* __restrict__ WT, const float* __restrict__ bias,
              float* __restrict__ C, int M, int N, int K, int act)
{
  __shared__ float4 As4[128 * 32];
  const int tx = threadIdx.x, ty = threadIdx.y;
  const int tid = ty * 32 + tx;
  const int n0 = blockIdx.x * 32, m0 = blockIdx.y * 32;
  const int K4 = K >> 2;

  for (int c = tid; c < K4 * 32; c += 256) {
    int k4 = c % K4, m = c / K4;
    int row = m0 + m;
    if (rowsrc) row = rowsrc[row];
    As4[k4 * 32 + m] = *(const float4*)(A + (size_t)row * K + k4 * 4);
  }
  __syncthreads();

  float acc[4] = {0,0,0,0};
  const int n = n0 + tx;
  const float* pb = WT + n;

  float bc[4], bn_[4];
#pragma unroll
  for (int kk = 0; kk < 4; ++kk) bc[kk] = pb[(size_t)kk * N];
  for (int k4 = 0; k4 < K4; ++k4) {
    int nk4 = (k4 + 1 < K4) ? (k4 + 1) : 0;
    const float* pn = pb + (size_t)nk4 * 4 * N;
#pragma unroll
    for (int kk = 0; kk < 4; ++kk) bn_[kk] = pn[(size_t)kk * N];
    float4 a0 = As4[k4 * 32 + ty * 4 + 0];
    float4 a1 = As4[k4 * 32 + ty * 4 + 1];
    float4 a2 = As4[k4 * 32 + ty * 4 + 2];
    float4 a3 = As4[k4 * 32 + ty * 4 + 3];
#pragma unroll
    for (int kk = 0; kk < 4; ++kk) {
      float b = bc[kk];
      acc[0] += ((const float*)&a0)[kk] * b;
      acc[1] += ((const float*)&a1)[kk] * b;
      acc[2] += ((const float*)&a2)[kk] * b;
      acc[3] += ((const float*)&a3)[kk] * b;
    }
#pragma unroll
    for (int qq = 0; qq < 4; ++qq) bc[qq] = bn_[qq];
  }
  float bb = bias ? bias[n] : 0.f;
#pragma unroll
  for (int r = 0; r < 4; ++r) {
    float v = acc[r] + bb;
    if (act) v = (v >= 0.f) ? v : 0.01f * v;
    C[(size_t)(m0 + ty * 4 + r) * N + n] = v;
  }
}

// ---------------------------------------------------------------- small stages
__global__ void mbday_part(const float* __restrict__ mbf, float* __restrict__ part) {
  int d = blockIdx.x, sl = blockIdx.y, c = threadIdx.x;
  float s = 0.f;
  int base = d * 512 + sl * 64;
  for (int st = 0; st < 64; ++st) s += mbf[(size_t)(base + st) * 256 + c];
  part[(size_t)(d * 8 + sl) * 256 + c] = s;
}

__global__ void mbday_fin(const float* __restrict__ part, float* __restrict__ mbday) {
  int d = blockIdx.x, c = threadIdx.x;
  float s = 0.f;
#pragma unroll
  for (int p = 0; p < 8; ++p) s += part[(size_t)(d * 8 + p) * 256 + c];
  mbday[d * 256 + c] = s * (1.0f / 512.0f);
}

__global__ void daytopk_kernel(const float* __restrict__ mbday, const float* __restrict__ thd,
                               int* __restrict__ dayidx) {
  __shared__ float mbs[256];
  __shared__ float sim[256];
  __shared__ float red[256];
  __shared__ int   redi[256];
  const int d = blockIdx.x, t = threadIdx.x;
  mbs[t] = mbday[d * 256 + t];
  __syncthreads();
  red[t] = mbs[t] * mbs[t];
  __syncthreads();
  for (int o = 128; o; o >>= 1) { if (t < o) red[t] += red[t + o]; __syncthreads(); }
  float xn = sqrtf(red[0]);
  float v = -INFINITY;
  if (t < 240) {
    float dot = 0.f, yn2 = 0.f;
    for (int k = 0; k < 256; ++k) {
      float y = thd[t * 256 + k];
      dot += mbs[k] * y;
      yn2 += y * y;
    }
    float den = xn * sqrtf(yn2);
    v = (den > 0.f) ? dot / den : 0.f;
  }
  sim[t] = v;
  __syncthreads();
  for (int it = 0; it < 10; ++it) {
    red[t] = sim[t]; redi[t] = t;
    __syncthreads();
    for (int o = 128; o; o >>= 1) {
      if (t < o) {
        if (red[t + o] > red[t] || (red[t + o] == red[t] && redi[t + o] < redi[t])) {
          red[t] = red[t + o]; redi[t] = redi[t + o];
        }
      }
      __syncthreads();
    }
    if (t == 0) { int bi = redi[0]; dayidx[d * 10 + it] = bi; sim[bi] = -INFINITY; }
    __syncthreads();
  }
}

__global__ void rowsrc_kernel(const int* __restrict__ dayidx, int* __restrict__ rowsrc) {
  int r = blockIdx.x * 256 + threadIdx.x;
  if (r < NSAMP) rowsrc[r] = dayidx[r >> 9] * 512 + (r & 511);
}

__global__ void rownorm_kernel(const float* __restrict__ X, float* __restrict__ out, int rows) {
  int w = threadIdx.x >> 6;
  int lane = threadIdx.x & 63;
  int row = blockIdx.x * 4 + w;
  if (row >= rows) return;
  float4 x = *(const float4*)(X + (size_t)row * 256 + lane * 4);
  float s = x.x * x.x + x.y * x.y + x.z * x.z + x.w * x.w;
#pragma unroll
  for (int o = 32; o; o >>= 1) s += __shfl_down(s, o, 64);
  if (lane == 0) out[row] = sqrtf(s);
}

__global__ void qnorm_kernel(float* __restrict__ q, const float* __restrict__ qn) {
  int i = blockIdx.x * 256 + threadIdx.x;
  int row = i >> 8;
  float n = qn[row];
  q[i] = (n > 0.f) ? q[i] / n : 0.f;
}

__global__ void khT_kernel(const float* __restrict__ kh, const float* __restrict__ khn,
                           float* __restrict__ khT) {
  __shared__ float tile[32][33];
  int jb = blockIdx.x * 32;
  int kb = blockIdx.y * 32;
  int tx = threadIdx.x & 31, tyy = threadIdx.x >> 5;
  for (int rr = tyy; rr < 32; rr += 8) {
    float n = khn[jb + rr];
    float v = kh[(size_t)(jb + rr) * 256 + kb + tx];
    tile[rr][tx] = (n > 0.f) ? v / n : 0.f;
  }
  __syncthreads();
  for (int rr = tyy; rr < 32; rr += 8) {
    khT[(size_t)(kb + rr) * NSAMP + jb + tx] = tile[tx][rr];
  }
}

// ---------------------------------------------------------------- cs GEMM + top-10 (split, XCD-swizzled)
__global__ __launch_bounds__(256, 4)
void csmax_kernel(const float* __restrict__ qh, const float* __restrict__ khT,
                  float* __restrict__ topvp, int* __restrict__ topip)
{
  __shared__ float4 qs[256][2];
  __shared__ float csch[8 * 512];
  const int tid = threadIdx.x;
  const int split = blockIdx.x & 7;
  const int m0 = (blockIdx.x >> 3) * 8;
  {
    int k = tid;
    float4 v0, v1;
    v0.x = qh[(size_t)(m0 + 0) * 256 + k]; v0.y = qh[(size_t)(m0 + 1) * 256 + k];
    v0.z = qh[(size_t)(m0 + 2) * 256 + k]; v0.w = qh[(size_t)(m0 + 3) * 256 + k];
    v1.x = qh[(size_t)(m0 + 4) * 256 + k]; v1.y = qh[(size_t)(m0 + 5) * 256 + k];
    v1.z = qh[(size_t)(m0 + 6) * 256 + k]; v1.w = qh[(size_t)(m0 + 7) * 256 + k];
    qs[k][0] = v0; qs[k][1] = v1;
  }
  __syncthreads();
  const int lane = tid & 63;
  const int wv = tid >> 6;

  float tv0[10], tv1[10];
  int   tj0[10], tj1[10];
  int   tn0 = 0, tn1 = 0;
  float tmv0 = -INFINITY, tmv1 = -INFINITY;
  int   tmi0 = 0, tmi1 = 0;

  auto process_row = [&](int r, float (&tv)[10], int (&tj)[10], int& tn,
                         float& tmv, int& tmi, int jb) {
    float4 c0 = *(const float4*)&csch[r * 512 + lane * 8];
    float4 c1 = *(const float4*)&csch[r * 512 + lane * 8 + 4];
    float cv[8] = {c0.x, c0.y, c0.z, c0.w, c1.x, c1.y, c1.z, c1.w};
    const int cj0 = jb + lane * 8;
    while (true) {
      float bv = -INFINITY; int bj = 0x7fffffff;
#pragma unroll
      for (int u = 0; u < 8; ++u) {
        if (cv[u] > bv) { bv = cv[u]; bj = cj0 + u; }
      }
#pragma unroll
      for (int o = 32; o; o >>= 1) {
        float ov = __shfl_down(bv, o, 64);
        int   oj = __shfl_down(bj, o, 64);
        if (ov > bv || (ov == bv && oj < bj)) { bv = ov; bj = oj; }
      }
      bv = __shfl(bv, 0, 64); bj = __shfl(bj, 0, 64);
      bool take;
      if (tn < 10) take = true;
      else take = (bv > tmv) || (bv == tmv && bj < tmi);
      if (!take) break;
      if (tn < 10) {
#pragma unroll
        for (int s = 0; s < 10; ++s) if (s == tn) { tv[s] = bv; tj[s] = bj; }
        tn++;
        if (tn == 10) {
          float mv = tv[0]; int mi = tj[0];
#pragma unroll
          for (int s = 1; s < 10; ++s) {
            bool w = (tv[s] < mv) || (tv[s] == mv && tj[s] > mi);
            if (w) { mv = tv[s]; mi = tj[s]; }
          }
          tmv = mv; tmi = mi;
        }
      } else {
        int ms = 0; float mv = tv[0]; int mi = tj[0];
#pragma unroll
        for (int s = 1; s < 10; ++s) {
          bool w = (tv[s] < mv) || (tv[s] == mv && tj[s] > mi);
          if (w) { ms = s; mv = tv[s]; mi = tj[s]; }
        }
#pragma unroll
        for (int s = 0; s < 10; ++s) if (s == ms) { tv[s] = bv; tj[s] = bj; }
        mv = tv[0]; mi = tj[0];
#pragma unroll
        for (int s = 1; s < 10; ++s) {
          bool w = (tv[s] < mv) || (tv[s] == mv && tj[s] > mi);
          if (w) { mv = tv[s]; mi = tj[s]; }
        }
        tmv = mv; tmi = mi;
      }
#pragma unroll
      for (int u = 0; u < 8; ++u) if (cj0 + u == bj) cv[u] = -INFINITY;
    }
  };

  for (int ci = 0; ci < 5; ++ci) {
    const int ch = split * 5 + ci;
    const int jb = ch * 512;
    float acc[8][2];
#pragma unroll
    for (int r = 0; r < 8; ++r) { acc[r][0] = 0.f; acc[r][1] = 0.f; }
    const float* kp = khT + jb + tid;

    float b0c[4], b1c[4], b0n[4], b1n[4];
#pragma unroll
    for (int kk = 0; kk < 4; ++kk) {
      b0c[kk] = kp[(size_t)kk * NSAMP];
      b1c[kk] = kp[(size_t)kk * NSAMP + 256];
    }
    for (int k4 = 0; k4 < 64; ++k4) {
      int nk4 = (k4 + 1) & 63;
      const float* pn = kp + (size_t)nk4 * 4 * NSAMP;
#pragma unroll
      for (int kk = 0; kk < 4; ++kk) {
        b0n[kk] = pn[(size_t)kk * NSAMP];
        b1n[kk] = pn[(size_t)kk * NSAMP + 256];
      }
#pragma unroll
      for (int kk = 0; kk < 4; ++kk) {
        float4 qa = qs[k4 * 4 + kk][0];
        float4 qb = qs[k4 * 4 + kk][1];
        float b0 = b0c[kk], b1 = b1c[kk];
        acc[0][0] += qa.x * b0; acc[1][0] += qa.y * b0; acc[2][0] += qa.z * b0; acc[3][0] += qa.w * b0;
        acc[4][0] += qb.x * b0; acc[5][0] += qb.y * b0; acc[6][0] += qb.z * b0; acc[7][0] += qb.w * b0;
        acc[0][1] += qa.x * b1; acc[1][1] += qa.y * b1; acc[2][1] += qa.z * b1; acc[3][1] += qa.w * b1;
        acc[4][1] += qb.x * b1; acc[5][1] += qb.y * b1; acc[6][1] += qb.z * b1; acc[7][1] += qb.w * b1;
      }
#pragma unroll
      for (int qq = 0; qq < 4; ++qq) { b0c[qq] = b0n[qq]; b1c[qq] = b1n[qq]; }
    }
    __syncthreads();
#pragma unroll
    for (int r = 0; r < 8; ++r) {
      csch[r * 512 + tid] = acc[r][0];
      csch[r * 512 + 256 + tid] = acc[r][1];
    }
    __syncthreads();
    process_row(wv,     tv0, tj0, tn0, tmv0, tmi0, jb);
    process_row(wv + 4, tv1, tj1, tn1, tmv1, tmi1, jb);
  }
  __syncthreads();

  if (lane == 0) {
    int row0 = m0 + wv;
#pragma unroll
    for (int s = 0; s < 10; ++s) {
      topvp[(size_t)row0 * 80 + split * 10 + s] = tv0[s];
      topip[(size_t)row0 * 80 + split * 10 + s] = tj0[s];
    }
    int row1 = m0 + wv + 4;
#pragma unroll
    for (int s = 0; s < 10; ++s) {
      topvp[(size_t)row1 * 80 + split * 10 + s] = tv1[s];
      topip[(size_t)row1 * 80 + split * 10 + s] = tj1[s];
    }
  }
}

// merge 8 splits x 10 candidates -> global top-10 per row (value desc, idx asc)
__global__ void merge_topk(const float* __restrict__ topvp, const int* __restrict__ topip,
                           float* __restrict__ topv, int* __restrict__ topi)
{
  const int wv = threadIdx.x >> 6;
  const int lane = threadIdx.x & 63;
  const int row = blockIdx.x * 4 + wv;
  float v0 = topvp[(size_t)row * 80 + lane];
  int   i0 = topip[(size_t)row * 80 + lane];
  float v1 = (lane < 16) ? topvp[(size_t)row * 80 + 64 + lane] : -INFINITY;
  int   i1 = (lane < 16) ? topip[(size_t)row * 80 + 64 + lane] : 0x7fffffff;
  for (int s = 0; s < 10; ++s) {
    float bv = v0; int bj = i0;
    if (v1 > bv || (v1 == bv && i1 < bj)) { bv = v1; bj = i1; }
#pragma unroll
    for (int o = 1; o < 64; o <<= 1) {
      float ov = __shfl_xor(bv, o, 64);
      int   oj = __shfl_xor(bj, o, 64);
      if (ov > bv || (ov == bv && oj < bj)) { bv = ov; bj = oj; }
    }
    if (lane == 0) { topv[row * 10 + s] = bv; topi[row * 10 + s] = bj; }
    if (i0 == bj) { v0 = -INFINITY; i0 = 0x7fffffff; }
    if (i1 == bj) { v1 = -INFINITY; i1 = 0x7fffffff; }
  }
}

// ---------------------------------------------------------------- final: agg + fc
__global__ void final_kernel(const float* __restrict__ mb, const float* __restrict__ kh,
                             const float* __restrict__ topv, const int* __restrict__ topi,
                             const float* __restrict__ fcW, const float* __restrict__ fcb,
                             float* __restrict__ y)
{
  __shared__ float red[256];
  int n = blockIdx.x, c = threadIdx.x;
  float agg = 0.f;
#pragma unroll
  for (int k = 0; k < 10; ++k) {
    float w = topv[n * 10 + k] / 10.0f;
    int idx = topi[n * 10 + k];
    agg += w * kh[(size_t)idx * 256 + c];
  }
  float val = fcW[c] * mb[(size_t)n * 256 + c] + fcW[256 + c] * agg;
  red[c] = val;
  __syncthreads();
  for (int o = 128; o; o >>= 1) { if (c < o) red[c] += red[c + o]; __syncthreads(); }
  if (c == 0) y[n] = red[0] + fcb[0];
}

// ---------------------------------------------------------------- launch
extern "C" void kernel_launch(void* const* d_in, const int* in_sizes, int n_in,
                              void* d_out, int out_size, void* d_ws, size_t ws_size,
                              hipStream_t stream)
{
  const float* inp    = (const float*)d_in[0];
  const float* trainh = (const float*)d_in[1];
  const float* thd    = (const float*)d_in[2];
  const float* Wih0   = (const float*)d_in[3];
  const float* Whh0   = (const float*)d_in[4];
  const float* bih0   = (const float*)d_in[5];
  const float* bhh0   = (const float*)d_in[6];
  const float* Wih1   = (const float*)d_in[7];
  const float* Whh1   = (const float*)d_in[8];
  const float* bih1   = (const float*)d_in[9];
  const float* bhh1   = (const float*)d_in[10];
  const float* lin0W  = (const float*)d_in[11];
  const float* lin0b  = (const float*)d_in[12];
  const float* lin1W  = (const float*)d_in[13];
  const float* lin1b  = (const float*)d_in[14];
  const float* lin2W  = (const float*)d_in[15];
  const float* lin2b  = (const float*)d_in[16];
  const float* p1W    = (const float*)d_in[17];
  const float* p2W    = (const float*)d_in[18];
  const float* fcW    = (const float*)d_in[19];
  const float* fcb    = (const float*)d_in[20];

  float* ws = (float*)d_ws;
  float* WT_hh0 = ws + 0;          // 256x768 (packed [k4][u][col][kk])
  float* WTcat  = ws + 196608;     // 512x768 (packed)
  float* WT_l0  = ws + 589824;     // 256x512
  float* WT_l1  = ws + 720896;     // 512x512
  float* WT_l2  = ws + 983040;     // 512x256
  float* WT_p1  = ws + 1114112;    // 256x256
  float* WT_p2  = ws + 1179648;    // 256x256
  float* hrow   = ws + 1245184;    // 2048x256
  float* mb1    = ws + 3342336;    // 2048x512 (reused for topk candidates)
  float* mb2    = ws + 4390912;    // 2048x512 (WT_ih0 during GRU; mbday partials later)
  float* mbf    = ws + 5439488;    // 2048x256
  float* mbday  = ws + 5963776;    // 4x256
  float* qbuf   = ws + 5964800;    // 2048x256
  float* kh     = ws + 6489088;    // 20480x256
  float* khT    = ws + 11731968;   // 256x20480 (normalized)
  float* khn    = ws + 16974848;   // 20480
  float* qn     = ws + 16995328;   // 2048
  float* topv   = ws + 16997376;   // 2048x10
  int*   dayidx = (int*)(ws + 17017856);
  int*   rowsrc = (int*)(ws + 17017920);
  int*   topi   = (int*)(ws + 17038400);
  float* topvp  = mb1;                       // 2048x80
  int*   topip  = (int*)(mb1 + 163840);      // 2048x80
  float* WT_ih0 = mb2;                       // 6x768 (used only during gru_fused)
  float* mbpart = mb2;                       // 4x8x256 (after GRU)

  PrepArgs pa;
  pa.src[0] = Whh0;  pa.dst[0] = WT_hh0; pa.N[0] = 768; pa.K[0] = 256; pa.ro[0] = 0;   pa.pk[0] = 1;
  pa.src[1] = Wih1;  pa.dst[1] = WTcat;  pa.N[1] = 768; pa.K[1] = 256; pa.ro[1] = 0;   pa.pk[1] = 1;
  pa.src[2] = Whh1;  pa.dst[2] = WTcat;  pa.N[2] = 768; pa.K[2] = 256; pa.ro[2] = 256; pa.pk[2] = 1;
  pa.src[3] = lin0W; pa.dst[3] = WT_l0;  pa.N[3] = 512; pa.K[3] = 256; pa.ro[3] = 0;   pa.pk[3] = 0;
  pa.src[4] = lin1W; pa.dst[4] = WT_l1;  pa.N[4] = 512; pa.K[4] = 512; pa.ro[4] = 0;   pa.pk[4] = 0;
  pa.src[5] = lin2W; pa.dst[5] = WT_l2;  pa.N[5] = 256; pa.K[5] = 512; pa.ro[5] = 0;   pa.pk[5] = 0;
  pa.src[6] = p1W;   pa.dst[6] = WT_p1;  pa.N[6] = 256; pa.K[6] = 256; pa.ro[6] = 0;   pa.pk[6] = 0;
  pa.src[7] = p2W;   pa.dst[7] = WT_p2;  pa.N[7] = 256; pa.K[7] = 256; pa.ro[7] = 0;   pa.pk[7] = 0;
  pa.src[8] = Wih0;  pa.dst[8] = WT_ih0; pa.N[8] = 768; pa.K[8] = 6;   pa.ro[8] = 0;   pa.pk[8] = 0;
  prep_weights<<<dim3(64, 9), dim3(256), 0, stream>>>(pa);

  gru_fused<<<256, 512, 0, stream>>>(inp, WT_hh0, WTcat, WT_ih0, bih0, bhh0, bih1, bhh1, hrow);

  gemm_act<<<dim3(16, 64), dim3(32, 8), 0, stream>>>(hrow, nullptr, WT_l0, lin0b, mb1, 2048, 512, 256, 1);
  gemm_act<<<dim3(16, 64), dim3(32, 8), 0, stream>>>(mb1, nullptr, WT_l1, lin1b, mb2, 2048, 512, 512, 1);
  gemm_act<<<dim3(8, 64),  dim3(32, 8), 0, stream>>>(mb2, nullptr, WT_l2, lin2b, mbf, 2048, 256, 512, 1);

  mbday_part<<<dim3(4, 8), 256, 0, stream>>>(mbf, mbpart);
  mbday_fin<<<4, 256, 0, stream>>>(mbpart, mbday);
  daytopk_kernel<<<4, 256, 0, stream>>>(mbday, thd, dayidx);
  rowsrc_kernel<<<80, 256, 0, stream>>>(dayidx, rowsrc);

  gemm_act<<<dim3(8, 640), dim3(32, 8), 0, stream>>>(trainh, rowsrc, WT_p2, nullptr, kh, 20480, 256, 256, 0);
  gemm_act<<<dim3(8, 64),  dim3(32, 8), 0, stream>>>(mbf, nullptr, WT_p1, nullptr, qbuf, 2048, 256, 256, 0);

  rownorm_kernel<<<5120, 256, 0, stream>>>(kh, khn, 20480);
  rownorm_kernel<<<512, 256, 0, stream>>>(qbuf, qn, 2048);
  qnorm_kernel<<<2048, 256, 0, stream>>>(qbuf, qn);
  khT_kernel<<<dim3(640, 8), 256, 0, stream>>>(kh, khn, khT);

  csmax_kernel<<<2048, 256, 0, stream>>>(qbuf, khT, topvp, topip);
  merge_topk<<<512, 256, 0, stream>>>(topvp, topip, topv, topi);
  final_kernel<<<2048, 256, 0, stream>>>(mbf, kh, topv, topi, fcW, fcb, (float*)d_out);

  (void)in_sizes; (void)n_in; (void)out_size; (void)ws_size;
}

// Round 8
// 3242.116 us; speedup vs baseline: 1.2240x; 1.2240x over previous
//
#include <hip/hip_runtime.h>
#include <cmath>
#include <cstdint>

#define D_FEAT 6
#define T_SEQ  60
#define HID    256
#define G3     768
#define NROW   2048
#define NSAMP  20480

__device__ __forceinline__ float sigmoidf_(float x) { return 1.0f / (1.0f + expf(-x)); }

// ---------------------------------------------------------------- weight prep
struct PrepArgs {
  const float* src[9];
  float* dst[9];
  int N[9], K[9], ro[9], pk[9];
};

__global__ void prep_weights(PrepArgs a) {
  int seg = blockIdx.y;
  const float* S = a.src[seg];
  float* D = a.dst[seg];
  int N = a.N[seg], K = a.K[seg], ro = a.ro[seg], pk = a.pk[seg];
  int total = N * K;
  for (int i = blockIdx.x * blockDim.x + threadIdx.x; i < total; i += gridDim.x * blockDim.x) {
    int n = i / K, k = i - n * K;
    if (pk) {
      // packed layout for GRU: [k/4][u][col][k%4], u = n>>8, col = n&255
      int u = n >> 8, cn = n & 255;
      int kg = k + ro;
      D[(size_t)((kg >> 2) * 3 + u) * 1024 + cn * 4 + (kg & 3)] = S[i];
    } else {
      D[(size_t)(k + ro) * N + n] = S[i];   // WT[k][n] = W[n][k]
    }
  }
}

// ---------------------------------------------------------------- persistent fused GRU v11
// Grid 256 x 512 threads (the only clean shape: 128-VGPR budget honored).
// Dual-col DS fix, register-safe this time. Thread (cp = tid&127, q = tid>>7)
// computes quarter-K partials for 6 outputs {cp,cp+128}x{r,z,n} over all 8
// rows: each LDS A-read feeds 48 FMAs (v9: 24) -> ds_read_b128 per thread
// per step 768 -> 384 (DS was ~69% of v9's step time).
// Register discipline (v10 failed at ~150 live): NO B ping-pong (JIT loads,
// unroll-4 window schedules them), NO A prefetch, NO persistent bias regs
// (combined biases in LDS stash), NO xn regs across kloop2 (all threads park
// xn in exchange slots 72..103 and q0 re-reads). Kloop live ~90 < 128.
// Gates: q0 only, one col at a time (live ~60). 4 barriers/step.
#define FMA8(alo, ahi, b, accrow) \
  accrow[0] += alo.x * (b); accrow[1] += alo.y * (b); accrow[2] += alo.z * (b); accrow[3] += alo.w * (b); \
  accrow[4] += ahi.x * (b); accrow[5] += ahi.y * (b); accrow[6] += ahi.z * (b); accrow[7] += ahi.w * (b);

#define KQSTEP(CMP) { \
    float4 alo = *(const float4*)(Ap); \
    float4 ahi = *(const float4*)(Ap + 4); \
    Ap += 8; \
    FMA8(alo, ahi, b0.CMP, pA[0]); FMA8(alo, ahi, b1.CMP, pA[1]); FMA8(alo, ahi, b2.CMP, pA[2]); \
    FMA8(alo, ahi, c0.CMP, pB[0]); FMA8(alo, ahi, c1.CMP, pB[1]); FMA8(alo, ahi, c2.CMP, pB[2]); }

#define ST8(dst, s) { \
  float4 v_; v_.x=(s)[0]; v_.y=(s)[1]; v_.z=(s)[2]; v_.w=(s)[3]; *(float4*)(dst) = v_; \
  v_.x=(s)[4]; v_.y=(s)[5]; v_.z=(s)[6]; v_.w=(s)[7]; *(float4*)((dst)+4) = v_; }

__device__ __forceinline__ void kloop64d(const float* __restrict__ A,   // LDS, this quarter's 64 k-rows (broadcast)
                                         const float* __restrict__ B,   // packed weights, pre-offset (q,cp)
                                         float (&pA)[3][8], float (&pB)[3][8])
{
  const float* Ap = A;
#pragma unroll 4
  for (int k4 = 0; k4 < 16; ++k4) {
    const float* Bk = B + (size_t)k4 * 3072;
    float4 b0 = *(const float4*)(Bk);          // u=0, col cp
    float4 b1 = *(const float4*)(Bk + 1024);   // u=1, col cp
    float4 b2 = *(const float4*)(Bk + 2048);   // u=2, col cp
    float4 c0 = *(const float4*)(Bk + 512);    // u=0, col cp+128
    float4 c1 = *(const float4*)(Bk + 1536);
    float4 c2 = *(const float4*)(Bk + 2560);
    KQSTEP(x) KQSTEP(y) KQSTEP(z) KQSTEP(w)
  }
}

__global__ __launch_bounds__(512, 1)
void gru_fused(const float* __restrict__ inp, const float* __restrict__ Whh0p,
               const float* __restrict__ Wcatp, const float* __restrict__ WTih0,
               const float* __restrict__ bih0, const float* __restrict__ bhh0,
               const float* __restrict__ bih1, const float* __restrict__ bhh1,
               float* __restrict__ hrow)
{
  __shared__ float h0A[2048], h0B[2048];   // [col*8 + row] ping-pong
  __shared__ float h1A[2048], h1B[2048];
  __shared__ float xls[2880];              // [(i*60+t)*8 + row]
  __shared__ float bls[2048];              // 8 x 256: cbr0,cbz0,bin0,bhn0,cbr1,cbz1,bin1,bhn1
  __shared__ float exch[256 * 104];        // per col: [src3][{r,z,n}x8]=72 | xn[src4][8]=32

  const int tid = threadIdx.x;
  const int cp  = tid & 127;               // first col; second is cp+128
  const int q   = tid >> 7;                // K-quarter
  const int m0  = blockIdx.x * 8;

  for (int c = tid; c < 2880; c += 512) {
    int row = c / 360, it = c - row * 360;
    xls[it * 8 + row] = inp[(size_t)(m0 + row) * 360 + it];
  }
  for (int c = tid; c < 2048; c += 512) { h0A[c] = 0.f; h1A[c] = 0.f; }
  if (tid < 256) {
    int c = tid;
    bls[c]          = bih0[c]       + bhh0[c];         // cbr0
    bls[256 + c]    = bih0[256 + c] + bhh0[256 + c];   // cbz0
    bls[512 + c]    = bih0[512 + c];                   // bin0
    bls[768 + c]    = bhh0[512 + c];                   // bhn0
    bls[1024 + c]   = bih1[c]       + bhh1[c];         // cbr1
    bls[1280 + c]   = bih1[256 + c] + bhh1[256 + c];   // cbz1
    bls[1536 + c]   = bih1[512 + c];                   // bin1
    bls[1792 + c]   = bhh1[512 + c];                   // bhn1
  }
  __syncthreads();

  const int aoff = q << 9;                 // q*64 k-rows * 8
  const float* Bhh  = Whh0p + (size_t)(q * 16) * 3072 + cp * 4;
  const float* Bct0 = Wcatp + (size_t)(q * 16) * 3072 + cp * 4;
  const float* Bct1 = Wcatp + (size_t)(64 + q * 16) * 3072 + cp * 4;
  float* exc0 = exch + cp * 104;
  float* exc1 = exch + (cp + 128) * 104;

#pragma unroll 1
  for (int t = 0; t < T_SEQ; ++t) {
    const float* h0cur = (t & 1) ? h0B : h0A;
    float*       h0nxt = (t & 1) ? h0A : h0B;
    const float* h1cur = (t & 1) ? h1B : h1A;
    float*       h1nxt = (t & 1) ? h1A : h1B;

    // ================= layer 0 =================
    float pA[3][8], pB[3][8];
#pragma unroll
    for (int u = 0; u < 3; ++u)
#pragma unroll
      for (int r = 0; r < 8; ++r) { pA[u][r] = 0.f; pB[u][r] = 0.f; }
    kloop64d(h0cur + aoff, Bhh, pA, pB);

    if (q != 0) {
      float* e0 = exc0 + (q - 1) * 24;
      float* e1 = exc1 + (q - 1) * 24;
#pragma unroll
      for (int u = 0; u < 3; ++u) {
        ST8(e0 + u * 8, pA[u]);
        ST8(e1 + u * 8, pB[u]);
      }
    }
    __syncthreads();

    if (q == 0) {
      // ---- col A (cp) ----
      {
#pragma unroll
        for (int s = 0; s < 3; ++s)
#pragma unroll
          for (int u = 0; u < 3; ++u)
#pragma unroll
            for (int r = 0; r < 8; ++r) pA[u][r] += exc0[s * 24 + u * 8 + r];
        float xw0[8], xw1[8], xw2[8];
        float cbr = bls[cp], cbz = bls[256 + cp], bin = bls[512 + cp], bhn = bls[768 + cp];
#pragma unroll
        for (int r = 0; r < 8; ++r) { xw0[r] = cbr; xw1[r] = cbz; xw2[r] = bin; }
#pragma unroll
        for (int i = 0; i < 6; ++i) {
          float4 xlo = *(const float4*)&xls[(i * 60 + t) * 8];
          float4 xhi = *(const float4*)&xls[(i * 60 + t) * 8 + 4];
          float w0 = WTih0[i * G3 + cp];
          float w1 = WTih0[i * G3 + 256 + cp];
          float w2 = WTih0[i * G3 + 512 + cp];
          FMA8(xlo, xhi, w0, xw0); FMA8(xlo, xhi, w1, xw1); FMA8(xlo, xhi, w2, xw2);
        }
        float hn[8];
#pragma unroll
        for (int r = 0; r < 8; ++r) {
          float rr = sigmoidf_(xw0[r] + pA[0][r]);
          float zz = sigmoidf_(xw1[r] + pA[1][r]);
          float nn = tanhf(xw2[r] + rr * (pA[2][r] + bhn));
          hn[r] = (1.f - zz) * nn + zz * h0cur[cp * 8 + r];
        }
        ST8(&h0nxt[cp * 8], hn);
      }
      // ---- col B (cp+128) ----
      {
#pragma unroll
        for (int s = 0; s < 3; ++s)
#pragma unroll
          for (int u = 0; u < 3; ++u)
#pragma unroll
            for (int r = 0; r < 8; ++r) pB[u][r] += exc1[s * 24 + u * 8 + r];
        float xw0[8], xw1[8], xw2[8];
        float cbr = bls[cp + 128], cbz = bls[256 + cp + 128];
        float bin = bls[512 + cp + 128], bhn = bls[768 + cp + 128];
#pragma unroll
        for (int r = 0; r < 8; ++r) { xw0[r] = cbr; xw1[r] = cbz; xw2[r] = bin; }
#pragma unroll
        for (int i = 0; i < 6; ++i) {
          float4 xlo = *(const float4*)&xls[(i * 60 + t) * 8];
          float4 xhi = *(const float4*)&xls[(i * 60 + t) * 8 + 4];
          float w0 = WTih0[i * G3 + cp + 128];
          float w1 = WTih0[i * G3 + 256 + cp + 128];
          float w2 = WTih0[i * G3 + 512 + cp + 128];
          FMA8(xlo, xhi, w0, xw0); FMA8(xlo, xhi, w1, xw1); FMA8(xlo, xhi, w2, xw2);
        }
        float hn[8];
#pragma unroll
        for (int r = 0; r < 8; ++r) {
          float rr = sigmoidf_(xw0[r] + pB[0][r]);
          float zz = sigmoidf_(xw1[r] + pB[1][r]);
          float nn = tanhf(xw2[r] + rr * (pB[2][r] + bhn));
          hn[r] = (1.f - zz) * nn + zz * h0cur[(cp + 128) * 8 + r];
        }
        ST8(&h0nxt[(cp + 128) * 8], hn);
      }
    }
    __syncthreads();

    // ================= layer 1 =================
#pragma unroll
    for (int u = 0; u < 3; ++u)
#pragma unroll
      for (int r = 0; r < 8; ++r) { pA[u][r] = 0.f; pB[u][r] = 0.f; }
    kloop64d(h0nxt + aoff, Bct0, pA, pB);       // x-part: r,z into [0],[1]; xn into [2]
    // park xn in exchange (slots 72..103), nothing extra live across kloop2
    ST8(exc0 + 72 + q * 8, pA[2]);
    ST8(exc1 + 72 + q * 8, pB[2]);
#pragma unroll
    for (int r = 0; r < 8; ++r) { pA[2][r] = 0.f; pB[2][r] = 0.f; }
    kloop64d(h1cur + aoff, Bct1, pA, pB);       // h-part: r,z continue; hn into [2]

    if (q != 0) {
      float* e0 = exc0 + (q - 1) * 24;
      float* e1 = exc1 + (q - 1) * 24;
      ST8(e0,      pA[0]); ST8(e0 + 8,  pA[1]); ST8(e0 + 16, pA[2]);
      ST8(e1,      pB[0]); ST8(e1 + 8,  pB[1]); ST8(e1 + 16, pB[2]);
    }
    __syncthreads();

    if (q == 0) {
      // ---- col A ----
      {
#pragma unroll
        for (int s = 0; s < 3; ++s)
#pragma unroll
          for (int r = 0; r < 8; ++r) {
            pA[0][r] += exc0[s * 24 + r];
            pA[1][r] += exc0[s * 24 + 8 + r];
            pA[2][r] += exc0[s * 24 + 16 + r];
          }
        float xn[8];
#pragma unroll
        for (int r = 0; r < 8; ++r)
          xn[r] = exc0[72 + r] + exc0[80 + r] + exc0[88 + r] + exc0[96 + r];
        float cbr = bls[1024 + cp], cbz = bls[1280 + cp];
        float bin = bls[1536 + cp], bhn = bls[1792 + cp];
        float hn[8];
#pragma unroll
        for (int r = 0; r < 8; ++r) {
          float rr = sigmoidf_(pA[0][r] + cbr);
          float zz = sigmoidf_(pA[1][r] + cbz);
          float nn = tanhf(xn[r] + bin + rr * (pA[2][r] + bhn));
          hn[r] = (1.f - zz) * nn + zz * h1cur[cp * 8 + r];
        }
        ST8(&h1nxt[cp * 8], hn);
      }
      // ---- col B ----
      {
#pragma unroll
        for (int s = 0; s < 3; ++s)
#pragma unroll
          for (int r = 0; r < 8; ++r) {
            pB[0][r] += exc1[s * 24 + r];
            pB[1][r] += exc1[s * 24 + 8 + r];
            pB[2][r] += exc1[s * 24 + 16 + r];
          }
        float xn[8];
#pragma unroll
        for (int r = 0; r < 8; ++r)
          xn[r] = exc1[72 + r] + exc1[80 + r] + exc1[88 + r] + exc1[96 + r];
        float cbr = bls[1024 + cp + 128], cbz = bls[1280 + cp + 128];
        float bin = bls[1536 + cp + 128], bhn = bls[1792 + cp + 128];
        float hn[8];
#pragma unroll
        for (int r = 0; r < 8; ++r) {
          float rr = sigmoidf_(pB[0][r] + cbr);
          float zz = sigmoidf_(pB[1][r] + cbz);
          float nn = tanhf(xn[r] + bin + rr * (pB[2][r] + bhn));
          hn[r] = (1.f - zz) * nn + zz * h1cur[(cp + 128) * 8 + r];
        }
        ST8(&h1nxt[(cp + 128) * 8], hn);
      }
    }
    __syncthreads();
  }

  // T_SEQ even: final h1 state is in h1A
  if (q == 0) {
#pragma unroll
    for (int r = 0; r < 8; ++r) {
      hrow[(size_t)(m0 + r) * 256 + cp]       = h1A[cp * 8 + r];
      hrow[(size_t)(m0 + r) * 256 + cp + 128] = h1A[(cp + 128) * 8 + r];
    }
  }
}

// ---------------------------------------------------------------- generic GEMM
__global__ __launch_bounds__(256, 2)
void gemm_act(const float* __restrict__ A, const int* __restrict__ rowsrc,
              const float* __restrict__ WT, const float* __restrict__ bias,
              float* __restrict__ C, int M, int N, int K, int act)
{
  __shared__ float4 As4[128 * 32];
  const int tx = threadIdx.x, ty = threadIdx.y;
  const int tid = ty * 32 + tx;
  const int n0 = blockIdx.x * 32, m0 = blockIdx.y * 32;
  const int K4 = K >> 2;

  for (int c = tid; c < K4 * 32; c += 256) {
    int k4 = c % K4, m = c / K4;
    int row = m0 + m;
    if (rowsrc) row = rowsrc[row];
    As4[k4 * 32 + m] = *(const float4*)(A + (size_t)row * K + k4 * 4);
  }
  __syncthreads();

  float acc[4] = {0,0,0,0};
  const int n = n0 + tx;
  const float* pb = WT + n;

  float bc[4], bn_[4];
#pragma unroll
  for (int kk = 0; kk < 4; ++kk) bc[kk] = pb[(size_t)kk * N];
  for (int k4 = 0; k4 < K4; ++k4) {
    int nk4 = (k4 + 1 < K4) ? (k4 + 1) : 0;
    const float* pn = pb + (size_t)nk4 * 4 * N;
#pragma unroll
    for (int kk = 0; kk < 4; ++kk) bn_[kk] = pn[(size_t)kk * N];
    float4 a0 = As4[k4 * 32 + ty * 4 + 0];
    float4 a1 = As4[k4 * 32 + ty * 4 + 1];
    float4 a2 = As4[k4 * 32 + ty * 4 + 2];
    float4 a3 = As4[k4 * 32 + ty * 4 + 3];
#pragma unroll
    for (int kk = 0; kk < 4; ++kk) {
      float b = bc[kk];
      acc[0] += ((const float*)&a0)[kk] * b;
      acc[1] += ((const float*)&a1)[kk] * b;
      acc[2] += ((const float*)&a2)[kk] * b;
      acc[3] += ((const float*)&a3)[kk] * b;
    }
#pragma unroll
    for (int qq = 0; qq < 4; ++qq) bc[qq] = bn_[qq];
  }
  float bb = bias ? bias[n] : 0.f;
#pragma unroll
  for (int r = 0; r < 4; ++r) {
    float v = acc[r] + bb;
    if (act) v = (v >= 0.f) ? v : 0.01f * v;
    C[(size_t)(m0 + ty * 4 + r) * N + n] = v;
  }
}

// ---------------------------------------------------------------- small stages
__global__ void mbday_part(const float* __restrict__ mbf, float* __restrict__ part) {
  int d = blockIdx.x, sl = blockIdx.y, c = threadIdx.x;
  float s = 0.f;
  int base = d * 512 + sl * 64;
  for (int st = 0; st < 64; ++st) s += mbf[(size_t)(base + st) * 256 + c];
  part[(size_t)(d * 8 + sl) * 256 + c] = s;
}

__global__ void mbday_fin(const float* __restrict__ part, float* __restrict__ mbday) {
  int d = blockIdx.x, c = threadIdx.x;
  float s = 0.f;
#pragma unroll
  for (int p = 0; p < 8; ++p) s += part[(size_t)(d * 8 + p) * 256 + c];
  mbday[d * 256 + c] = s * (1.0f / 512.0f);
}

__global__ void daytopk_kernel(const float* __restrict__ mbday, const float* __restrict__ thd,
                               int* __restrict__ dayidx) {
  __shared__ float mbs[256];
  __shared__ float sim[256];
  __shared__ float red[256];
  __shared__ int   redi[256];
  const int d = blockIdx.x, t = threadIdx.x;
  mbs[t] = mbday[d * 256 + t];
  __syncthreads();
  red[t] = mbs[t] * mbs[t];
  __syncthreads();
  for (int o = 128; o; o >>= 1) { if (t < o) red[t] += red[t + o]; __syncthreads(); }
  float xn = sqrtf(red[0]);
  float v = -INFINITY;
  if (t < 240) {
    float dot = 0.f, yn2 = 0.f;
    for (int k = 0; k < 256; ++k) {
      float y = thd[t * 256 + k];
      dot += mbs[k] * y;
      yn2 += y * y;
    }
    float den = xn * sqrtf(yn2);
    v = (den > 0.f) ? dot / den : 0.f;
  }
  sim[t] = v;
  __syncthreads();
  for (int it = 0; it < 10; ++it) {
    red[t] = sim[t]; redi[t] = t;
    __syncthreads();
    for (int o = 128; o; o >>= 1) {
      if (t < o) {
        if (red[t + o] > red[t] || (red[t + o] == red[t] && redi[t + o] < redi[t])) {
          red[t] = red[t + o]; redi[t] = redi[t + o];
        }
      }
      __syncthreads();
    }
    if (t == 0) { int bi = redi[0]; dayidx[d * 10 + it] = bi; sim[bi] = -INFINITY; }
    __syncthreads();
  }
}

__global__ void rowsrc_kernel(const int* __restrict__ dayidx, int* __restrict__ rowsrc) {
  int r = blockIdx.x * 256 + threadIdx.x;
  if (r < NSAMP) rowsrc[r] = dayidx[r >> 9] * 512 + (r & 511);
}

__global__ void rownorm_kernel(const float* __restrict__ X, float* __restrict__ out, int rows) {
  int w = threadIdx.x >> 6;
  int lane = threadIdx.x & 63;
  int row = blockIdx.x * 4 + w;
  if (row >= rows) return;
  float4 x = *(const float4*)(X + (size_t)row * 256 + lane * 4);
  float s = x.x * x.x + x.y * x.y + x.z * x.z + x.w * x.w;
#pragma unroll
  for (int o = 32; o; o >>= 1) s += __shfl_down(s, o, 64);
  if (lane == 0) out[row] = sqrtf(s);
}

__global__ void qnorm_kernel(float* __restrict__ q, const float* __restrict__ qn) {
  int i = blockIdx.x * 256 + threadIdx.x;
  int row = i >> 8;
  float n = qn[row];
  q[i] = (n > 0.f) ? q[i] / n : 0.f;
}

__global__ void khT_kernel(const float* __restrict__ kh, const float* __restrict__ khn,
                           float* __restrict__ khT) {
  __shared__ float tile[32][33];
  int jb = blockIdx.x * 32;
  int kb = blockIdx.y * 32;
  int tx = threadIdx.x & 31, tyy = threadIdx.x >> 5;
  for (int rr = tyy; rr < 32; rr += 8) {
    float n = khn[jb + rr];
    float v = kh[(size_t)(jb + rr) * 256 + kb + tx];
    tile[rr][tx] = (n > 0.f) ? v / n : 0.f;
  }
  __syncthreads();
  for (int rr = tyy; rr < 32; rr += 8) {
    khT[(size_t)(kb + rr) * NSAMP + jb + tx] = tile[tx][rr];
  }
}

// ---------------------------------------------------------------- cs GEMM + top-10 (split, XCD-swizzled)
__global__ __launch_bounds__(256, 4)
void csmax_kernel(const float* __restrict__ qh, const float* __restrict__ khT,
                  float* __restrict__ topvp, int* __restrict__ topip)
{
  __shared__ float4 qs[256][2];
  __shared__ float csch[8 * 512];
  const int tid = threadIdx.x;
  const int split = blockIdx.x & 7;
  const int m0 = (blockIdx.x >> 3) * 8;
  {
    int k = tid;
    float4 v0, v1;
    v0.x = qh[(size_t)(m0 + 0) * 256 + k]; v0.y = qh[(size_t)(m0 + 1) * 256 + k];
    v0.z = qh[(size_t)(m0 + 2) * 256 + k]; v0.w = qh[(size_t)(m0 + 3) * 256 + k];
    v1.x = qh[(size_t)(m0 + 4) * 256 + k]; v1.y = qh[(size_t)(m0 + 5) * 256 + k];
    v1.z = qh[(size_t)(m0 + 6) * 256 + k]; v1.w = qh[(size_t)(m0 + 7) * 256 + k];
    qs[k][0] = v0; qs[k][1] = v1;
  }
  __syncthreads();
  const int lane = tid & 63;
  const int wv = tid >> 6;

  float tv0[10], tv1[10];
  int   tj0[10], tj1[10];
  int   tn0 = 0, tn1 = 0;
  float tmv0 = -INFINITY, tmv1 = -INFINITY;
  int   tmi0 = 0, tmi1 = 0;

  auto process_row = [&](int r, float (&tv)[10], int (&tj)[10], int& tn,
                         float& tmv, int& tmi, int jb) {
    float4 c0 = *(const float4*)&csch[r * 512 + lane * 8];
    float4 c1 = *(const float4*)&csch[r * 512 + lane * 8 + 4];
    float cv[8] = {c0.x, c0.y, c0.z, c0.w, c1.x, c1.y, c1.z, c1.w};
    const int cj0 = jb + lane * 8;
    while (true) {
      float bv = -INFINITY; int bj = 0x7fffffff;
#pragma unroll
      for (int u = 0; u < 8; ++u) {
        if (cv[u] > bv) { bv = cv[u]; bj = cj0 + u; }
      }
#pragma unroll
      for (int o = 32; o; o >>= 1) {
        float ov = __shfl_down(bv, o, 64);
        int   oj = __shfl_down(bj, o, 64);
        if (ov > bv || (ov == bv && oj < bj)) { bv = ov; bj = oj; }
      }
      bv = __shfl(bv, 0, 64); bj = __shfl(bj, 0, 64);
      bool take;
      if (tn < 10) take = true;
      else take = (bv > tmv) || (bv == tmv && bj < tmi);
      if (!take) break;
      if (tn < 10) {
#pragma unroll
        for (int s = 0; s < 10; ++s) if (s == tn) { tv[s] = bv; tj[s] = bj; }
        tn++;
        if (tn == 10) {
          float mv = tv[0]; int mi = tj[0];
#pragma unroll
          for (int s = 1; s < 10; ++s) {
            bool w = (tv[s] < mv) || (tv[s] == mv && tj[s] > mi);
            if (w) { mv = tv[s]; mi = tj[s]; }
          }
          tmv = mv; tmi = mi;
        }
      } else {
        int ms = 0; float mv = tv[0]; int mi = tj[0];
#pragma unroll
        for (int s = 1; s < 10; ++s) {
          bool w = (tv[s] < mv) || (tv[s] == mv && tj[s] > mi);
          if (w) { ms = s; mv = tv[s]; mi = tj[s]; }
        }
#pragma unroll
        for (int s = 0; s < 10; ++s) if (s == ms) { tv[s] = bv; tj[s] = bj; }
        mv = tv[0]; mi = tj[0];
#pragma unroll
        for (int s = 1; s < 10; ++s) {
          bool w = (tv[s] < mv) || (tv[s] == mv && tj[s] > mi);
          if (w) { mv = tv[s]; mi = tj[s]; }
        }
        tmv = mv; tmi = mi;
      }
#pragma unroll
      for (int u = 0; u < 8; ++u) if (cj0 + u == bj) cv[u] = -INFINITY;
    }
  };

  for (int ci = 0; ci < 5; ++ci) {
    const int ch = split * 5 + ci;
    const int jb = ch * 512;
    float acc[8][2];
#pragma unroll
    for (int r = 0; r < 8; ++r) { acc[r][0] = 0.f; acc[r][1] = 0.f; }
    const float* kp = khT + jb + tid;

    float b0c[4], b1c[4], b0n[4], b1n[4];
#pragma unroll
    for (int kk = 0; kk < 4; ++kk) {
      b0c[kk] = kp[(size_t)kk * NSAMP];
      b1c[kk] = kp[(size_t)kk * NSAMP + 256];
    }
    for (int k4 = 0; k4 < 64; ++k4) {
      int nk4 = (k4 + 1) & 63;
      const float* pn = kp + (size_t)nk4 * 4 * NSAMP;
#pragma unroll
      for (int kk = 0; kk < 4; ++kk) {
        b0n[kk] = pn[(size_t)kk * NSAMP];
        b1n[kk] = pn[(size_t)kk * NSAMP + 256];
      }
#pragma unroll
      for (int kk = 0; kk < 4; ++kk) {
        float4 qa = qs[k4 * 4 + kk][0];
        float4 qb = qs[k4 * 4 + kk][1];
        float b0 = b0c[kk], b1 = b1c[kk];
        acc[0][0] += qa.x * b0; acc[1][0] += qa.y * b0; acc[2][0] += qa.z * b0; acc[3][0] += qa.w * b0;
        acc[4][0] += qb.x * b0; acc[5][0] += qb.y * b0; acc[6][0] += qb.z * b0; acc[7][0] += qb.w * b0;
        acc[0][1] += qa.x * b1; acc[1][1] += qa.y * b1; acc[2][1] += qa.z * b1; acc[3][1] += qa.w * b1;
        acc[4][1] += qb.x * b1; acc[5][1] += qb.y * b1; acc[6][1] += qb.z * b1; acc[7][1] += qb.w * b1;
      }
#pragma unroll
      for (int qq = 0; qq < 4; ++qq) { b0c[qq] = b0n[qq]; b1c[qq] = b1n[qq]; }
    }
    __syncthreads();
#pragma unroll
    for (int r = 0; r < 8; ++r) {
      csch[r * 512 + tid] = acc[r][0];
      csch[r * 512 + 256 + tid] = acc[r][1];
    }
    __syncthreads();
    process_row(wv,     tv0, tj0, tn0, tmv0, tmi0, jb);
    process_row(wv + 4, tv1, tj1, tn1, tmv1, tmi1, jb);
  }
  __syncthreads();

  if (lane == 0) {
    int row0 = m0 + wv;
#pragma unroll
    for (int s = 0; s < 10; ++s) {
      topvp[(size_t)row0 * 80 + split * 10 + s] = tv0[s];
      topip[(size_t)row0 * 80 + split * 10 + s] = tj0[s];
    }
    int row1 = m0 + wv + 4;
#pragma unroll
    for (int s = 0; s < 10; ++s) {
      topvp[(size_t)row1 * 80 + split * 10 + s] = tv1[s];
      topip[(size_t)row1 * 80 + split * 10 + s] = tj1[s];
    }
  }
}

// merge 8 splits x 10 candidates -> global top-10 per row (value desc, idx asc)
__global__ void merge_topk(const float* __restrict__ topvp, const int* __restrict__ topip,
                           float* __restrict__ topv, int* __restrict__ topi)
{
  const int wv = threadIdx.x >> 6;
  const int lane = threadIdx.x & 63;
  const int row = blockIdx.x * 4 + wv;
  float v0 = topvp[(size_t)row * 80 + lane];
  int   i0 = topip[(size_t)row * 80 + lane];
  float v1 = (lane < 16) ? topvp[(size_t)row * 80 + 64 + lane] : -INFINITY;
  int   i1 = (lane < 16) ? topip[(size_t)row * 80 + 64 + lane] : 0x7fffffff;
  for (int s = 0; s < 10; ++s) {
    float bv = v0; int bj = i0;
    if (v1 > bv || (v1 == bv && i1 < bj)) { bv = v1; bj = i1; }
#pragma unroll
    for (int o = 1; o < 64; o <<= 1) {
      float ov = __shfl_xor(bv, o, 64);
      int   oj = __shfl_xor(bj, o, 64);
      if (ov > bv || (ov == bv && oj < bj)) { bv = ov; bj = oj; }
    }
    if (lane == 0) { topv[row * 10 + s] = bv; topi[row * 10 + s] = bj; }
    if (i0 == bj) { v0 = -INFINITY; i0 = 0x7fffffff; }
    if (i1 == bj) { v1 = -INFINITY; i1 = 0x7fffffff; }
  }
}

// ---------------------------------------------------------------- final: agg + fc
__global__ void final_kernel(const float* __restrict__ mb, const float* __restrict__ kh,
                             const float* __restrict__ topv, const int* __restrict__ topi,
                             const float* __restrict__ fcW, const float* __restrict__ fcb,
                             float* __restrict__ y)
{
  __shared__ float red[256];
  int n = blockIdx.x, c = threadIdx.x;
  float agg = 0.f;
#pragma unroll
  for (int k = 0; k < 10; ++k) {
    float w = topv[n * 10 + k] / 10.0f;
    int idx = topi[n * 10 + k];
    agg += w * kh[(size_t)idx * 256 + c];
  }
  float val = fcW[c] * mb[(size_t)n * 256 + c] + fcW[256 + c] * agg;
  red[c] = val;
  __syncthreads();
  for (int o = 128; o; o >>= 1) { if (c < o) red[c] += red[c + o]; __syncthreads(); }
  if (c == 0) y[n] = red[0] + fcb[0];
}

// ---------------------------------------------------------------- launch
extern "C" void kernel_launch(void* const* d_in, const int* in_sizes, int n_in,
                              void* d_out, int out_size, void* d_ws, size_t ws_size,
                              hipStream_t stream)
{
  const float* inp    = (const float*)d_in[0];
  const float* trainh = (const float*)d_in[1];
  const float* thd    = (const float*)d_in[2];
  const float* Wih0   = (const float*)d_in[3];
  const float* Whh0   = (const float*)d_in[4];
  const float* bih0   = (const float*)d_in[5];
  const float* bhh0   = (const float*)d_in[6];
  const float* Wih1   = (const float*)d_in[7];
  const float* Whh1   = (const float*)d_in[8];
  const float* bih1   = (const float*)d_in[9];
  const float* bhh1   = (const float*)d_in[10];
  const float* lin0W  = (const float*)d_in[11];
  const float* lin0b  = (const float*)d_in[12];
  const float* lin1W  = (const float*)d_in[13];
  const float* lin1b  = (const float*)d_in[14];
  const float* lin2W  = (const float*)d_in[15];
  const float* lin2b  = (const float*)d_in[16];
  const float* p1W    = (const float*)d_in[17];
  const float* p2W    = (const float*)d_in[18];
  const float* fcW    = (const float*)d_in[19];
  const float* fcb    = (const float*)d_in[20];

  float* ws = (float*)d_ws;
  float* WT_hh0 = ws + 0;          // 256x768 (packed [k4][u][col][kk])
  float* WTcat  = ws + 196608;     // 512x768 (packed)
  float* WT_l0  = ws + 589824;     // 256x512
  float* WT_l1  = ws + 720896;     // 512x512
  float* WT_l2  = ws + 983040;     // 512x256
  float* WT_p1  = ws + 1114112;    // 256x256
  float* WT_p2  = ws + 1179648;    // 256x256
  float* hrow   = ws + 1245184;    // 2048x256
  float* mb1    = ws + 3342336;    // 2048x512 (reused for topk candidates)
  float* mb2    = ws + 4390912;    // 2048x512 (WT_ih0 during GRU; mbday partials later)
  float* mbf    = ws + 5439488;    // 2048x256
  float* mbday  = ws + 5963776;    // 4x256
  float* qbuf   = ws + 5964800;    // 2048x256
  float* kh     = ws + 6489088;    // 20480x256
  float* khT    = ws + 11731968;   // 256x20480 (normalized)
  float* khn    = ws + 16974848;   // 20480
  float* qn     = ws + 16995328;   // 2048
  float* topv   = ws + 16997376;   // 2048x10
  int*   dayidx = (int*)(ws + 17017856);
  int*   rowsrc = (int*)(ws + 17017920);
  int*   topi   = (int*)(ws + 17038400);
  float* topvp  = mb1;                       // 2048x80
  int*   topip  = (int*)(mb1 + 163840);      // 2048x80
  float* WT_ih0 = mb2;                       // 6x768 (used only during gru_fused)
  float* mbpart = mb2;                       // 4x8x256 (after GRU)

  PrepArgs pa;
  pa.src[0] = Whh0;  pa.dst[0] = WT_hh0; pa.N[0] = 768; pa.K[0] = 256; pa.ro[0] = 0;   pa.pk[0] = 1;
  pa.src[1] = Wih1;  pa.dst[1] = WTcat;  pa.N[1] = 768; pa.K[1] = 256; pa.ro[1] = 0;   pa.pk[1] = 1;
  pa.src[2] = Whh1;  pa.dst[2] = WTcat;  pa.N[2] = 768; pa.K[2] = 256; pa.ro[2] = 256; pa.pk[2] = 1;
  pa.src[3] = lin0W; pa.dst[3] = WT_l0;  pa.N[3] = 512; pa.K[3] = 256; pa.ro[3] = 0;   pa.pk[3] = 0;
  pa.src[4] = lin1W; pa.dst[4] = WT_l1;  pa.N[4] = 512; pa.K[4] = 512; pa.ro[4] = 0;   pa.pk[4] = 0;
  pa.src[5] = lin2W; pa.dst[5] = WT_l2;  pa.N[5] = 256; pa.K[5] = 512; pa.ro[5] = 0;   pa.pk[5] = 0;
  pa.src[6] = p1W;   pa.dst[6] = WT_p1;  pa.N[6] = 256; pa.K[6] = 256; pa.ro[6] = 0;   pa.pk[6] = 0;
  pa.src[7] = p2W;   pa.dst[7] = WT_p2;  pa.N[7] = 256; pa.K[7] = 256; pa.ro[7] = 0;   pa.pk[7] = 0;
  pa.src[8] = Wih0;  pa.dst[8] = WT_ih0; pa.N[8] = 768; pa.K[8] = 6;   pa.ro[8] = 0;   pa.pk[8] = 0;
  prep_weights<<<dim3(64, 9), dim3(256), 0, stream>>>(pa);

  gru_fused<<<256, 512, 0, stream>>>(inp, WT_hh0, WTcat, WT_ih0, bih0, bhh0, bih1, bhh1, hrow);

  gemm_act<<<dim3(16, 64), dim3(32, 8), 0, stream>>>(hrow, nullptr, WT_l0, lin0b, mb1, 2048, 512, 256, 1);
  gemm_act<<<dim3(16, 64), dim3(32, 8), 0, stream>>>(mb1, nullptr, WT_l1, lin1b, mb2, 2048, 512, 512, 1);
  gemm_act<<<dim3(8, 64),  dim3(32, 8), 0, stream>>>(mb2, nullptr, WT_l2, lin2b, mbf, 2048, 256, 512, 1);

  mbday_part<<<dim3(4, 8), 256, 0, stream>>>(mbf, mbpart);
  mbday_fin<<<4, 256, 0, stream>>>(mbpart, mbday);
  daytopk_kernel<<<4, 256, 0, stream>>>(mbday, thd, dayidx);
  rowsrc_kernel<<<80, 256, 0, stream>>>(dayidx, rowsrc);

  gemm_act<<<dim3(8, 640), dim3(32, 8), 0, stream>>>(trainh, rowsrc, WT_p2, nullptr, kh, 20480, 256, 256, 0);
  gemm_act<<<dim3(8, 64),  dim3(32, 8), 0, stream>>>(mbf, nullptr, WT_p1, nullptr, qbuf, 2048, 256, 256, 0);

  rownorm_kernel<<<5120, 256, 0, stream>>>(kh, khn, 20480);
  rownorm_kernel<<<512, 256, 0, stream>>>(qbuf, qn, 2048);
  qnorm_kernel<<<2048, 256, 0, stream>>>(qbuf, qn);
  khT_kernel<<<dim3(640, 8), 256, 0, stream>>>(kh, khn, khT);

  csmax_kernel<<<2048, 256, 0, stream>>>(qbuf, khT, topvp, topip);
  merge_topk<<<512, 256, 0, stream>>>(topvp, topip, topv, topi);
  final_kernel<<<2048, 256, 0, stream>>>(mbf, kh, topv, topi, fcW, fcb, (float*)d_out);

  (void)in_sizes; (void)n_in; (void)out_size; (void)ws_size;
}